// Round 5
// baseline (250.178 us; speedup 1.0000x reference)
//
#include <hip/hip_runtime.h>
#include <math.h>

#define TOK 16384
#define DD  2048
#define EE  64
#define MT  32           // tokens per block
#define BK  32           // k per chunk
#define NKC 32           // chunks per K-half (K-half = 1024)

typedef _Float16 half8  __attribute__((ext_vector_type(8)));
typedef float    floatx4 __attribute__((ext_vector_type(4)));

// ---- W pre-split: f32 -> (hi,lo) f16, frag-major layout ----
// wf frag index ((ct*64+kcg)*2+s)*64+lane, 8 halves each.
// ct 0..3 = gate col-tiles (cols (ct&3)*16+cl), ct 4..7 = noise col-tiles.
__global__ void build_wf(const float* __restrict__ Wg, const float* __restrict__ Wn,
                         _Float16* __restrict__ wf) {
  int tid  = blockIdx.x * 256 + threadIdx.x;   // 32768 threads
  int lane = tid & 63;
  int kc   = (tid >> 6) & 63;
  int ct   = tid >> 12;                        // 0..7
  int col  = (ct & 3) * 16 + (lane & 15);
  int k    = kc * 32 + (lane >> 4) * 8;
  const float* W = (ct < 4) ? Wg : Wn;
  const float* src = W + (size_t)col * DD + k;
  float4 a = *reinterpret_cast<const float4*>(src);
  float4 b = *reinterpret_cast<const float4*>(src + 4);
  float v[8] = {a.x, a.y, a.z, a.w, b.x, b.y, b.z, b.w};
  half8 hi, lo;
#pragma unroll
  for (int j = 0; j < 8; ++j) {
    _Float16 h = (_Float16)v[j];
    hi[j] = h;
    lo[j] = (_Float16)(v[j] - (float)h);
  }
  size_t base = (((size_t)(ct * 64 + kc) * 2 + 0) * 64 + lane) * 8;
  *reinterpret_cast<half8*>(wf + base)       = hi;
  *reinterpret_cast<half8*>(wf + base + 512) = lo;
}

// Block = 256 thr = 4 waves: wave w -> (ch = w&1 col-half, kh = w>>1 K-half).
// Wave computes 32 tokens x (16 gate+16 noise cols)x2 for K in [kh*1024, +1024).
// NO barrier / NO LDS in the K-loop; LDS only for end-of-kernel merge+epilogue.
// LDS: Pacc[32][132] @0 (16896) | Vb[32][66] @16896 | Eb[32][66] @25344
//      isum @33792 | ti @33920 | tp @34176  -> 34432 B
__global__ __launch_bounds__(256, 2)
void gating_kernel(const float* __restrict__ x, const float* __restrict__ rn,
                   const _Float16* __restrict__ wf, const float* __restrict__ bg,
                   float* __restrict__ out,
                   float* __restrict__ cnt_g, float* __restrict__ psum_g) {
  __shared__ char smem[34432];
  float* Pacc = (float*)smem;                  // stride 132
  float* Vb   = (float*)(smem + 16896);        // stride 66
  float* Eb   = (float*)(smem + 25344);        // stride 66
  float* isum = (float*)(smem + 33792);
  int*   ti   = (int*)(smem + 33920);
  float* tp   = (float*)(smem + 34176);

  const int t  = threadIdx.x;
  const int w  = t >> 6;
  const int ch = w & 1;        // col-half: experts [ch*32, +32)
  const int kh = w >> 1;       // K-half
  const int l  = t & 63;
  const int q  = l >> 4;
  const int cl = l & 15;
  const int t0 = blockIdx.x * MT;

  // x row pointers: lane covers rows (mt*16+cl), k-window q*8..q*8+8 per chunk
  const float* xr0 = x + (size_t)(t0 + cl) * DD + kh * (NKC * BK) + q * 8;
  const float* xr1 = xr0 + (size_t)16 * DD;
  const half8* wfp = (const half8*)wf;
  // 4 ct per wave: j=0,1 gate cols (ch*32 + j*16 + cl), j=2,3 noise same cols
  const int cts[4] = {2 * ch, 2 * ch + 1, 4 + 2 * ch, 5 + 2 * ch};

  floatx4 acc[2][4];
#pragma unroll
  for (int mt = 0; mt < 2; ++mt)
#pragma unroll
    for (int j = 0; j < 4; ++j) acc[mt][j] = (floatx4)0.f;

  float4 xr[2][2][2];   // [parity][mt][half]
  half8  Bf[2][4][2];   // [parity][j][s]

#define LOAD_CHUNK(kc, p)                                                        \
  {                                                                              \
    const int off = (kc) * BK;                                                   \
    xr[p][0][0] = *reinterpret_cast<const float4*>(xr0 + off);                   \
    xr[p][0][1] = *reinterpret_cast<const float4*>(xr0 + off + 4);               \
    xr[p][1][0] = *reinterpret_cast<const float4*>(xr1 + off);                   \
    xr[p][1][1] = *reinterpret_cast<const float4*>(xr1 + off + 4);               \
    const int kcg = kh * NKC + (kc);                                             \
    _Pragma("unroll")                                                            \
    for (int j = 0; j < 4; ++j) {                                                \
      _Pragma("unroll")                                                          \
      for (int s = 0; s < 2; ++s)                                                \
        Bf[p][j][s] = wfp[((size_t)(cts[j] * 64 + kcg) * 2 + s) * 64 + l];       \
    }                                                                            \
  }

  LOAD_CHUNK(0, 0)

#pragma unroll 2
  for (int kc = 0; kc < NKC; ++kc) {
    const int cur = kc & 1;
    if (kc + 1 < NKC) LOAD_CHUNK(kc + 1, cur ^ 1)

    // convert x chunk -> hi/lo f16 fragments (in-register)
    half8 Ah[2], Al[2];
#pragma unroll
    for (int mt = 0; mt < 2; ++mt) {
      float v[8] = {xr[cur][mt][0].x, xr[cur][mt][0].y, xr[cur][mt][0].z, xr[cur][mt][0].w,
                    xr[cur][mt][1].x, xr[cur][mt][1].y, xr[cur][mt][1].z, xr[cur][mt][1].w};
#pragma unroll
      for (int j = 0; j < 8; ++j) {
        _Float16 h = (_Float16)v[j];
        Ah[mt][j] = h;
        Al[mt][j] = (_Float16)(v[j] - (float)h);
      }
    }
    // split-2 product: hi*hi + hi*lo + lo*hi (24 MFMA, 8 independent chains)
#pragma unroll
    for (int mt = 0; mt < 2; ++mt)
#pragma unroll
      for (int j = 0; j < 4; ++j)
        acc[mt][j] = __builtin_amdgcn_mfma_f32_16x16x32_f16(Ah[mt], Bf[cur][j][0], acc[mt][j], 0, 0, 0);
#pragma unroll
    for (int mt = 0; mt < 2; ++mt)
#pragma unroll
      for (int j = 0; j < 4; ++j)
        acc[mt][j] = __builtin_amdgcn_mfma_f32_16x16x32_f16(Ah[mt], Bf[cur][j][1], acc[mt][j], 0, 0, 0);
#pragma unroll
    for (int mt = 0; mt < 2; ++mt)
#pragma unroll
      for (int j = 0; j < 4; ++j)
        acc[mt][j] = __builtin_amdgcn_mfma_f32_16x16x32_f16(Al[mt], Bf[cur][j][0], acc[mt][j], 0, 0, 0);
  }
#undef LOAD_CHUNK

  // ---- split-K merge: kh=1 waves -> LDS ----
  if (kh == 1) {
#pragma unroll
    for (int mt = 0; mt < 2; ++mt)
#pragma unroll
      for (int j = 0; j < 4; ++j) {
        const int cf = ((j >> 1) ? 64 : 0) + ch * 32 + (j & 1) * 16 + cl;
#pragma unroll
        for (int r = 0; r < 4; ++r)
          Pacc[(mt * 16 + q * 4 + r) * 132 + cf] = acc[mt][j][r];
      }
  }
  __syncthreads();

  if (kh == 0) {
    // epilogue operand loads (latency exposed once; negligible)
    float bgv[2], rnv[2][4][2];
#pragma unroll
    for (int j = 0; j < 2; ++j) bgv[j] = bg[ch * 32 + j * 16 + cl];
#pragma unroll
    for (int mt = 0; mt < 2; ++mt)
#pragma unroll
      for (int r = 0; r < 4; ++r)
#pragma unroll
        for (int j = 0; j < 2; ++j)
          rnv[mt][r][j] = rn[(size_t)(t0 + mt * 16 + q * 4 + r) * EE + ch * 32 + j * 16 + cl];

#pragma unroll
    for (int mt = 0; mt < 2; ++mt)
#pragma unroll
      for (int r = 0; r < 4; ++r) {
        const int tk = mt * 16 + q * 4 + r;   // C/D layout: row = q*4+r
#pragma unroll
        for (int j = 0; j < 2; ++j) {
          const int cg = ch * 32 + j * 16 + cl;
          float g  = acc[mt][j][r]     + Pacc[tk * 132 + cg]      + bgv[j];
          float h  = acc[mt][j + 2][r] + Pacc[tk * 132 + 64 + cg];
          float sp = (h > 20.f) ? h : log1pf(expf(h));
          float v  = g + rnv[mt][r][j] * (sp + 0.01f);
          Vb[tk * 66 + cg] = v;
          Eb[tk * 66 + cg] = expf(v);
        }
      }
  }
  __syncthreads();

  // ---- per-token top-2 + softmax denom (32 threads) ----
  if (t < MT) {
    float v1 = -1e30f, v2 = -1e30f;
    int   i1 = 0, i2 = 0;
    float s = 0.f;
    for (int e = 0; e < EE; ++e) {
      float v = Vb[t * 66 + e];
      s += Eb[t * 66 + e];
      if (v > v1)      { v2 = v1; i2 = i1; v1 = v; i1 = e; }
      else if (v > v2) { v2 = v;  i2 = e; }
    }
    isum[t] = 1.f / s;
    ti[t * 2 + 0] = i1; ti[t * 2 + 1] = i2;
    float e2 = expf(v2 - v1);
    float dn = 1.f + e2;
    tp[t * 2 + 0] = 1.f / dn;
    tp[t * 2 + 1] = e2 / dn;
  }
  __syncthreads();

  // ---- sparse out: patched zero-fill, coalesced (8 floats/thread) ----
  {
    const int m  = t >> 3;
    const int c0 = (t & 7) * 8;
    const int i1 = ti[m * 2 + 0], i2 = ti[m * 2 + 1];
    const float p1 = tp[m * 2 + 0], p2 = tp[m * 2 + 1];
    float o[8];
#pragma unroll
    for (int j = 0; j < 8; ++j) {
      const int col = c0 + j;
      o[j] = (col == i1) ? p1 : ((col == i2) ? p2 : 0.f);
    }
    float* dst = out + (size_t)(t0 + m) * EE + c0;
    *reinterpret_cast<float4*>(dst)     = make_float4(o[0], o[1], o[2], o[3]);
    *reinterpret_cast<float4*>(dst + 4) = make_float4(o[4], o[5], o[6], o[7]);
  }

  // ---- aux partials: per-expert psum & count ----
  if (t < EE) {
    float s = 0.f;
    int   cn = 0;
#pragma unroll
    for (int m = 0; m < MT; ++m) {
      s  += Eb[m * 66 + t] * isum[m];
      cn += (ti[m * 2 + 0] == t) + (ti[m * 2 + 1] == t);
    }
    atomicAdd(&psum_g[t], s);
    atomicAdd(&cnt_g[t], (float)cn);
  }
}

__global__ void aux_kernel(const float* __restrict__ cnt_g,
                           const float* __restrict__ psum_g,
                           float* __restrict__ out) {
  int e = threadIdx.x;  // 64 lanes, one wave
  float v = cnt_g[e] * psum_g[e];
#pragma unroll
  for (int o = 32; o > 0; o >>= 1) v += __shfl_down(v, o);
  if (e == 0)
    out[(size_t)TOK * EE] = v * ((float)EE / ((float)TOK * (float)TOK));
}

extern "C" void kernel_launch(void* const* d_in, const int* in_sizes, int n_in,
                              void* d_out, int out_size, void* d_ws, size_t ws_size,
                              hipStream_t stream) {
  const float* x  = (const float*)d_in[0];
  const float* rn = (const float*)d_in[1];
  const float* Wg = (const float*)d_in[2];
  const float* bg = (const float*)d_in[3];
  const float* Wn = (const float*)d_in[4];
  float* out    = (float*)d_out;
  float* cnt_g  = (float*)d_ws;
  float* psum_g = cnt_g + EE;
  _Float16* wf  = (_Float16*)((float*)d_ws + 128);   // 1 MiB of pre-split W frags

  hipMemsetAsync(d_ws, 0, 2 * EE * sizeof(float), stream);
  build_wf<<<128, 256, 0, stream>>>(Wg, Wn, wf);
  gating_kernel<<<TOK / MT, 256, 0, stream>>>(x, rn, wf, bg, out, cnt_g, psum_g);
  aux_kernel<<<1, 64, 0, stream>>>(cnt_g, psum_g, out);
}